// Round 1
// baseline (154.904 us; speedup 1.0000x reference)
//
#include <hip/hip_runtime.h>
#include <hip/hip_bf16.h>

typedef __attribute__((ext_vector_type(8))) __bf16 bf16x8;
typedef __attribute__((ext_vector_type(4))) float f32x4;

#define BM 128
#define BN 128
#define BK 32

__device__ inline void gload_lds16(const void* g, void* l) {
  __builtin_amdgcn_global_load_lds((__attribute__((address_space(1))) void*)g,
                                   (__attribute__((address_space(3))) void*)l,
                                   16, 0, 0);
}

// ---------------- QDQ: per-256-group absmax scale, degenerate FP4 grid ----------------
// scale = max(absmax, 1e-6); v = x/scale in [-1,1]; q in {0, +-0.5, +-1.0}; out = bf16(q*scale)
__global__ __launch_bounds__(256) void qdq_kernel(const float* __restrict__ x,
                                                  __hip_bfloat16* __restrict__ y,
                                                  int ngroups) {
  int g = (blockIdx.x << 2) + (threadIdx.x >> 6);
  if (g >= ngroups) return;
  int lane = threadIdx.x & 63;
  size_t base = (size_t)g * 256 + (size_t)lane * 4;
  float4 v = *reinterpret_cast<const float4*>(x + base);
  float amax = fmaxf(fmaxf(fabsf(v.x), fabsf(v.y)), fmaxf(fabsf(v.z), fabsf(v.w)));
#pragma unroll
  for (int off = 32; off > 0; off >>= 1)
    amax = fmaxf(amax, __shfl_xor(amax, off, 64));
  float scale = fmaxf(amax, 1e-6f);
  float in[4] = {v.x, v.y, v.z, v.w};
  union { ushort4 u4; __hip_bfloat16 h[4]; } o;
#pragma unroll
  for (int i = 0; i < 4; ++i) {
    float xv = in[i];
    float t = fabsf(xv / scale);
    float q = t < 0.25f ? 0.0f : (t < 0.75f ? 0.5f : 1.0f);
    float r = copysignf(q, xv) * scale;
    o.h[i] = __float2bfloat16(r);
  }
  *reinterpret_cast<ushort4*>(y + base) = o.u4;
}

// ---------------- GEMM: C[M,N] = A[M,K] * B[N,K]^T + bias, bf16 MFMA ----------------
__global__ __launch_bounds__(256) void gemm_bt_bias(
    const __hip_bfloat16* __restrict__ A,  // [M,K] qdq input
    const __hip_bfloat16* __restrict__ B,  // [N,K] qdq weight
    const float* __restrict__ bias,        // [N]
    float* __restrict__ C,                 // [M,N]
    int M, int N, int K) {
  __shared__ __hip_bfloat16 As[BM * BK];
  __shared__ __hip_bfloat16 Bs[BN * BK];

  const int tid = threadIdx.x;
  const int lane = tid & 63;
  const int wave = tid >> 6;
  const int wr = wave >> 1, wc = wave & 1;

  const int ntiles = N / BN;
  const int tm = blockIdx.x / ntiles, tn = blockIdx.x % ntiles;
  const int m0 = tm * BM, n0 = tn * BN;

  f32x4 acc[4][4];
#pragma unroll
  for (int i = 0; i < 4; ++i)
#pragma unroll
    for (int j = 0; j < 4; ++j)
      acc[i][j] = (f32x4){0.f, 0.f, 0.f, 0.f};

  // staging: idx in [0,512); each idx covers 8 bf16 = 16B; row = idx>>2, kchunk = idx&3
  const int idx0 = tid, idx1 = 256 + tid;
  const size_t ga0 = (size_t)(m0 + (idx0 >> 2)) * K + (size_t)((idx0 & 3) * 8);
  const size_t ga1 = (size_t)(m0 + (idx1 >> 2)) * K + (size_t)((idx1 & 3) * 8);
  const size_t gb0 = (size_t)(n0 + (idx0 >> 2)) * K + (size_t)((idx0 & 3) * 8);
  const size_t gb1 = (size_t)(n0 + (idx1 >> 2)) * K + (size_t)((idx1 & 3) * 8);

  const int fr = lane & 15;           // fragment row/col within 16
  const int kc = (lane >> 4) * 8;     // k-chunk offset (elems)

  for (int kt = 0; kt < K; kt += BK) {
    gload_lds16(A + ga0 + kt, As + (size_t)idx0 * 8);
    gload_lds16(A + ga1 + kt, As + (size_t)idx1 * 8);
    gload_lds16(B + gb0 + kt, Bs + (size_t)idx0 * 8);
    gload_lds16(B + gb1 + kt, Bs + (size_t)idx1 * 8);
    __syncthreads();

    bf16x8 af[4], bfr[4];
#pragma unroll
    for (int i = 0; i < 4; ++i)
      af[i] = *reinterpret_cast<const bf16x8*>(&As[(size_t)(wr * 64 + i * 16 + fr) * BK + kc]);
#pragma unroll
    for (int j = 0; j < 4; ++j)
      bfr[j] = *reinterpret_cast<const bf16x8*>(&Bs[(size_t)(wc * 64 + j * 16 + fr) * BK + kc]);

#pragma unroll
    for (int i = 0; i < 4; ++i)
#pragma unroll
      for (int j = 0; j < 4; ++j)
        acc[i][j] = __builtin_amdgcn_mfma_f32_16x16x32_bf16(af[i], bfr[j], acc[i][j], 0, 0, 0);

    __syncthreads();
  }

  // epilogue: C[row][col] = acc + bias[col]; col = lane&15 + j*16, row = (lane>>4)*4 + r + i*16
#pragma unroll
  for (int j = 0; j < 4; ++j) {
    const int col = n0 + wc * 64 + j * 16 + fr;
    const float bv = bias[col];
#pragma unroll
    for (int i = 0; i < 4; ++i) {
      const int row = m0 + wr * 64 + i * 16 + (lane >> 4) * 4;
#pragma unroll
      for (int r = 0; r < 4; ++r)
        C[(size_t)(row + r) * N + col] = acc[i][j][r] + bv;
    }
  }
}

extern "C" void kernel_launch(void* const* d_in, const int* in_sizes, int n_in,
                              void* d_out, int out_size, void* d_ws, size_t ws_size,
                              hipStream_t stream) {
  const float* x = (const float*)d_in[0];     // [M,K]
  const float* w = (const float*)d_in[1];     // [N,K]
  const float* bias = (const float*)d_in[2];  // [N]
  float* out = (float*)d_out;

  const int MK = in_sizes[0];
  const int NK = in_sizes[1];
  const int N = in_sizes[2];
  const int K = NK / N;
  const int M = MK / K;

  __hip_bfloat16* qx = (__hip_bfloat16*)d_ws;
  __hip_bfloat16* qw = qx + (size_t)MK;

  const int gx = MK / 256;  // groups in input
  const int gw = NK / 256;  // groups in weight
  qdq_kernel<<<(gx + 3) / 4, 256, 0, stream>>>(x, qx, gx);
  qdq_kernel<<<(gw + 3) / 4, 256, 0, stream>>>(w, qw, gw);

  dim3 grid((M / BM) * (N / BN));
  gemm_bt_bias<<<grid, 256, 0, stream>>>(qx, qw, bias, out, M, N, K);
}

// Round 2
// 133.780 us; speedup vs baseline: 1.1579x; 1.1579x over previous
//
#include <hip/hip_runtime.h>
#include <hip/hip_bf16.h>

typedef __attribute__((ext_vector_type(8))) __bf16 bf16x8;
typedef __attribute__((ext_vector_type(4))) float f32x4;

#define BM 256
#define BN 256
#define BK 32
#define THREADS 512
#define BUF_BYTES 32768          // (BM+BN)*BK*2  = A 16KB + B 16KB
#define BUF_ELEMS 16384

#define VM8() asm volatile("s_waitcnt vmcnt(8)" ::: "memory")
#define VM4() asm volatile("s_waitcnt vmcnt(4)" ::: "memory")
#define VM0() asm volatile("s_waitcnt vmcnt(0)" ::: "memory")

__device__ inline void gload_lds16(const void* g, void* l) {
  __builtin_amdgcn_global_load_lds((__attribute__((address_space(1))) void*)g,
                                   (__attribute__((address_space(3))) void*)l,
                                   16, 0, 0);
}

// ---------------- QDQ: per-256-group absmax scale, degenerate FP4 grid ----------------
// scale = max(absmax, 1e-6); v = x/scale in [-1,1]; q in {0, +-0.5, +-1.0}; out = bf16(q*scale)
__global__ __launch_bounds__(256) void qdq_kernel(const float* __restrict__ x,
                                                  __hip_bfloat16* __restrict__ y,
                                                  int ngroups) {
  int g = (blockIdx.x << 2) + (threadIdx.x >> 6);
  if (g >= ngroups) return;
  int lane = threadIdx.x & 63;
  size_t base = (size_t)g * 256 + (size_t)lane * 4;
  float4 v = *reinterpret_cast<const float4*>(x + base);
  float amax = fmaxf(fmaxf(fabsf(v.x), fabsf(v.y)), fmaxf(fabsf(v.z), fabsf(v.w)));
#pragma unroll
  for (int off = 32; off > 0; off >>= 1)
    amax = fmaxf(amax, __shfl_xor(amax, off, 64));
  float scale = fmaxf(amax, 1e-6f);
  float in[4] = {v.x, v.y, v.z, v.w};
  union { ushort4 u4; __hip_bfloat16 h[4]; } o;
#pragma unroll
  for (int i = 0; i < 4; ++i) {
    float xv = in[i];
    float t = fabsf(xv / scale);
    float q = t < 0.25f ? 0.0f : (t < 0.75f ? 0.5f : 1.0f);
    float r = copysignf(q, xv) * scale;
    o.h[i] = __float2bfloat16(r);
  }
  *reinterpret_cast<ushort4*>(y + base) = o.u4;
}

// ---------------- GEMM 256x256, 8 waves, triple-buffered counted-vmcnt pipeline ------
// LDS buffer layout (per buf, 32KB): A [256 rows][4 chunks of 16B], then B same.
// Swizzle: physical chunk = logical kchunk ^ (row & 3), applied on BOTH the
// global source address (gload_lds dest is linear) and the ds_read address.
__global__ __launch_bounds__(THREADS, 2) void gemm256(
    const __hip_bfloat16* __restrict__ A,  // [M,K]
    const __hip_bfloat16* __restrict__ B,  // [N,K]
    const float* __restrict__ bias,        // [N]
    float* __restrict__ C,                 // [M,N]
    int M, int N, int K) {
  extern __shared__ char smem[];
  const __hip_bfloat16* sb = (const __hip_bfloat16*)smem;

  const int tid = threadIdx.x;
  const int lane = tid & 63;
  const int wid = tid >> 6;
  const int wm = wid >> 2;   // 0..1  -> 128-row half of the M-tile
  const int wn = wid & 3;    // 0..3  -> 64-col strip of the N-tile
  const int fr = lane & 15;
  const int hi = lane >> 4;  // k-chunk 0..3

  // T1: bijective XCD swizzle (grid % 8 == 0 for this shape)
  const int nwg = gridDim.x;
  int bid = blockIdx.x;
  if ((nwg & 7) == 0) bid = (bid & 7) * (nwg >> 3) + (bid >> 3);
  const int ntn = N / BN;
  const int tm = bid / ntn, tn = bid % ntn;
  const int m0 = tm * BM, n0 = tn * BN;

  // staging: 512 threads x 16B cover 128 rows x 64B per round; 2 rounds per matrix
  const int srow = tid >> 2;                 // 0..127
  const int schunk = tid & 3;
  const int skch = schunk ^ (srow & 3);      // inverse-swizzled global k-chunk
  const size_t aS0 = (size_t)(m0 + srow) * K + (size_t)skch * 8;
  const size_t aS1 = (size_t)(m0 + 128 + srow) * K + (size_t)skch * 8;
  const size_t bS0 = (size_t)(n0 + srow) * K + (size_t)skch * 8;
  const size_t bS1 = (size_t)(n0 + 128 + srow) * K + (size_t)skch * 8;
  const int dst0 = tid * 16;                 // linear LDS byte offset (lane x 16)

#define STAGE(bufi, t2) do {                                   \
    char* bb = smem + (bufi) * BUF_BYTES;                      \
    const size_t ko = (size_t)(t2) * BK;                       \
    gload_lds16(A + aS0 + ko, bb + dst0);                      \
    gload_lds16(A + aS1 + ko, bb + 8192 + dst0);               \
    gload_lds16(B + bS0 + ko, bb + 16384 + dst0);              \
    gload_lds16(B + bS1 + ko, bb + 24576 + dst0);              \
  } while (0)

  f32x4 acc[8][4];
#pragma unroll
  for (int i = 0; i < 8; ++i)
#pragma unroll
    for (int j = 0; j < 4; ++j) acc[i][j] = (f32x4){0.f, 0.f, 0.f, 0.f};

  const int T = K / BK;
  STAGE(0, 0);
  STAGE(1, 1);

  // read offsets (elems): row = wm*128 + i*16 + fr; phys chunk = hi ^ (row&3) = hi ^ (fr&3)
  const int cw = (hi ^ (fr & 3)) * 8;
  const int aoff0 = (wm * 128 + fr) * BK + cw;
  const int boff0 = 8192 + (wn * 64 + fr) * BK + cw;

  int buf = 0;
  for (int t = 0; t < T; ++t) {
    if (t + 2 < T) {
      int b2 = buf + 2; if (b2 >= 3) b2 -= 3;
      STAGE(b2, t + 2);
    }
    // tile t resident: allow (tiles issued after t) * 4 outstanding
    if (t <= T - 3) { VM8(); } else if (t == T - 2) { VM4(); } else { VM0(); }
    __builtin_amdgcn_s_barrier();

    const __hip_bfloat16* ab = sb + buf * BUF_ELEMS;
    bf16x8 af[8], bfr[4];

    // sp0: A-frags 0..3, B-frags 0..1 -> 8 MFMA
#pragma unroll
    for (int i = 0; i < 4; ++i) af[i] = *(const bf16x8*)(ab + aoff0 + i * 512);
#pragma unroll
    for (int j = 0; j < 2; ++j) bfr[j] = *(const bf16x8*)(ab + boff0 + j * 512);
    __builtin_amdgcn_s_setprio(1);
#pragma unroll
    for (int i = 0; i < 4; ++i)
#pragma unroll
      for (int j = 0; j < 2; ++j)
        acc[i][j] = __builtin_amdgcn_mfma_f32_16x16x32_bf16(af[i], bfr[j], acc[i][j], 0, 0, 0);
    __builtin_amdgcn_s_setprio(0);
    __builtin_amdgcn_s_barrier();

    // sp1: A-frags 4..7 -> 8 MFMA
#pragma unroll
    for (int i = 4; i < 8; ++i) af[i] = *(const bf16x8*)(ab + aoff0 + i * 512);
    __builtin_amdgcn_s_setprio(1);
#pragma unroll
    for (int i = 4; i < 8; ++i)
#pragma unroll
      for (int j = 0; j < 2; ++j)
        acc[i][j] = __builtin_amdgcn_mfma_f32_16x16x32_bf16(af[i], bfr[j], acc[i][j], 0, 0, 0);
    __builtin_amdgcn_s_setprio(0);
    __builtin_amdgcn_s_barrier();

    // sp2: B-frags 2..3 -> 8 MFMA (A 0..3 reused from regs)
#pragma unroll
    for (int j = 2; j < 4; ++j) bfr[j] = *(const bf16x8*)(ab + boff0 + j * 512);
    __builtin_amdgcn_s_setprio(1);
#pragma unroll
    for (int i = 0; i < 4; ++i)
#pragma unroll
      for (int j = 2; j < 4; ++j)
        acc[i][j] = __builtin_amdgcn_mfma_f32_16x16x32_bf16(af[i], bfr[j], acc[i][j], 0, 0, 0);
    __builtin_amdgcn_s_setprio(0);
    __builtin_amdgcn_s_barrier();

    // sp3: A 4..7 x B 2..3 -> 8 MFMA (all from regs)
    __builtin_amdgcn_s_setprio(1);
#pragma unroll
    for (int i = 4; i < 8; ++i)
#pragma unroll
      for (int j = 2; j < 4; ++j)
        acc[i][j] = __builtin_amdgcn_mfma_f32_16x16x32_bf16(af[i], bfr[j], acc[i][j], 0, 0, 0);
    __builtin_amdgcn_s_setprio(0);
    __builtin_amdgcn_s_barrier();   // end-of-iter: protects buf[t%3] reuse at t+1's STAGE

    buf = (buf + 1 == 3) ? 0 : buf + 1;
  }
#undef STAGE

  // epilogue: C[row][col] = acc + bias[col]
#pragma unroll
  for (int j = 0; j < 4; ++j) {
    const int col = n0 + wn * 64 + j * 16 + fr;
    const float bv = bias[col];
#pragma unroll
    for (int i = 0; i < 8; ++i) {
      const int row0 = m0 + wm * 128 + i * 16 + hi * 4;
#pragma unroll
      for (int r = 0; r < 4; ++r)
        C[(size_t)(row0 + r) * N + col] = acc[i][j][r] + bv;
    }
  }
}

extern "C" void kernel_launch(void* const* d_in, const int* in_sizes, int n_in,
                              void* d_out, int out_size, void* d_ws, size_t ws_size,
                              hipStream_t stream) {
  const float* x = (const float*)d_in[0];     // [M,K]
  const float* w = (const float*)d_in[1];     // [N,K]
  const float* bias = (const float*)d_in[2];  // [N]
  float* out = (float*)d_out;

  const int MK = in_sizes[0];
  const int NK = in_sizes[1];
  const int N = in_sizes[2];
  const int K = NK / N;
  const int M = MK / K;

  __hip_bfloat16* qx = (__hip_bfloat16*)d_ws;
  __hip_bfloat16* qw = qx + (size_t)MK;

  const int gx = MK / 256;
  const int gw = NK / 256;
  qdq_kernel<<<(gx + 3) / 4, 256, 0, stream>>>(x, qx, gx);
  qdq_kernel<<<(gw + 3) / 4, 256, 0, stream>>>(w, qw, gw);

  hipFuncSetAttribute((const void*)gemm256, hipFuncAttributeMaxDynamicSharedMemorySize,
                      3 * BUF_BYTES);
  dim3 grid((M / BM) * (N / BN));
  gemm256<<<grid, dim3(THREADS), 3 * BUF_BYTES, stream>>>(qx, qw, bias, out, M, N, K);
}

// Round 3
// 121.415 us; speedup vs baseline: 1.2758x; 1.1018x over previous
//
#include <hip/hip_runtime.h>
#include <hip/hip_bf16.h>

typedef __attribute__((ext_vector_type(8))) __bf16 bf16x8;
typedef __attribute__((ext_vector_type(4))) float f32x4;

#define BM 256
#define BN 256
#define BK 32
#define THREADS 512
#define TILE_BYTES 32768   // per K-tile: A 16KB + B 16KB
#define NBUF 4             // 4 x 32KB = 128KB LDS, prefetch distance 3 tiles

#define FENCE() asm volatile("" ::: "memory")
#define VMCNT(n) asm volatile("s_waitcnt vmcnt(" #n ")" ::: "memory")

static __device__ inline void gload_lds16(const void* g, void* l) {
  __builtin_amdgcn_global_load_lds((__attribute__((address_space(1))) void*)g,
                                   (__attribute__((address_space(3))) void*)l,
                                   16, 0, 0);
}

// ---------------- QDQ: per-256-group absmax scale, degenerate FP4 grid ----------------
// scale = max(absmax, 1e-6); v = x/scale in [-1,1]; q in {0, +-0.5, +-1.0}; out = bf16(q*scale)
__global__ __launch_bounds__(256) void qdq_kernel(const float* __restrict__ x,
                                                  __hip_bfloat16* __restrict__ y,
                                                  int ngroups) {
  int g = (blockIdx.x << 2) + (threadIdx.x >> 6);
  if (g >= ngroups) return;
  int lane = threadIdx.x & 63;
  size_t base = (size_t)g * 256 + (size_t)lane * 4;
  float4 v = *reinterpret_cast<const float4*>(x + base);
  float amax = fmaxf(fmaxf(fabsf(v.x), fabsf(v.y)), fmaxf(fabsf(v.z), fabsf(v.w)));
#pragma unroll
  for (int off = 32; off > 0; off >>= 1)
    amax = fmaxf(amax, __shfl_xor(amax, off, 64));
  float scale = fmaxf(amax, 1e-6f);
  float in[4] = {v.x, v.y, v.z, v.w};
  union { ushort4 u4; __hip_bfloat16 h[4]; } o;
#pragma unroll
  for (int i = 0; i < 4; ++i) {
    float xv = in[i];
    float t = fabsf(xv / scale);
    float q = t < 0.25f ? 0.0f : (t < 0.75f ? 0.5f : 1.0f);
    float r = copysignf(q, xv) * scale;
    o.h[i] = __float2bfloat16(r);
  }
  *reinterpret_cast<ushort4*>(y + base) = o.u4;
}

// ---------------- GEMM 256x256, 8 waves, 4-buffer counted-vmcnt pipeline --------------
// LDS pair-line layout per tile: logical (row r, 16B-chunk c) lives at
//   line L = r>>1 (128B lines), slot S = (c + 4*(r&1)) ^ (L & 7)
// -> any 16 consecutive rows at fixed c spread over all 8 slots (2 lanes/slot = free).
// gload_lds writes linearly (base + lane*16); the global SOURCE address is the
// inverse permutation; ds_read uses the swizzled address. Both sides, same involution.
__global__ __launch_bounds__(THREADS, 2) void gemm256(
    const __hip_bfloat16* __restrict__ A,  // [M,K] qdq input (bf16)
    const __hip_bfloat16* __restrict__ B,  // [N,K] qdq weight (bf16)
    const float* __restrict__ bias,        // [N]
    float* __restrict__ C,                 // [M,N]
    int M, int N, int K) {
  extern __shared__ char smem[];

  const int tid = threadIdx.x;
  const int lane = tid & 63;
  const int wid = tid >> 6;
  const int wm = wid >> 2;   // 0..1 -> 128-row half
  const int wn = wid & 3;    // 0..3 -> 64-col strip
  const int fr = lane & 15;
  const int hi = lane >> 4;  // k-chunk 0..3

  // T1: bijective XCD swizzle (grid=512, %8==0)
  const int nwg = gridDim.x;
  int bid = blockIdx.x;
  if ((nwg & 7) == 0) bid = (bid & 7) * (nwg >> 3) + (bid >> 3);
  const int ntn = N / BN;
  const int tm = bid / ntn, tn = bid % ntn;
  const int m0 = tm * BM, n0 = tn * BN;

  // ---- staging source map (inverse of pair-line swizzle) ----
  // thread tid, load j: dest byte D=(j*512+tid)*16 -> L=j*64+(tid>>3), S=tid&7
  // u = S ^ (L&7) = (tid&7) ^ ((tid>>3)&7);  r = 2L + (u>>2);  c = u&3
  const int u = (tid & 7) ^ ((tid >> 3) & 7);
  const int c0 = (u & 3) * 8;                  // k-element offset of the 16B chunk
  const int r0 = 2 * (tid >> 3) + (u >> 2);    // row for j=0; j=1 adds 128
  const size_t gA0 = (size_t)(m0 + r0) * K + c0;
  const size_t gA1 = (size_t)(m0 + r0 + 128) * K + c0;
  const size_t gB0 = (size_t)(n0 + r0) * K + c0;
  const size_t gB1 = (size_t)(n0 + r0 + 128) * K + c0;
  const int d0 = tid * 16;

#define STAGE(bufi, tt) do {                                    \
    char* bb = smem + (size_t)(bufi) * TILE_BYTES;              \
    const size_t ko = (size_t)(tt) * BK;                        \
    gload_lds16(A + gA0 + ko, bb + d0);                         \
    gload_lds16(A + gA1 + ko, bb + d0 + 8192);                  \
    gload_lds16(B + gB0 + ko, bb + d0 + 16384);                 \
    gload_lds16(B + gB1 + ko, bb + d0 + 24576);                 \
  } while (0)

  // ---- swizzled read bases ----
  // A frag i: row R = wm*128 + i*16 + fr -> L = wm*64 + i*8 + (fr>>1), L&7 = fr>>1
  // slot S = (hi + 4*(fr&1)) ^ (fr>>1)  (same for A and B)
  const int S16 = ((hi + 4 * (fr & 1)) ^ (fr >> 1)) << 4;
  const int aBase = ((wm * 64 + (fr >> 1)) << 7) + S16;          // + i*1024
  const int bBase = 16384 + ((wn * 32 + (fr >> 1)) << 7) + S16;  // + j*1024

  f32x4 acc[8][4];
#pragma unroll
  for (int i = 0; i < 8; ++i)
#pragma unroll
    for (int j = 0; j < 4; ++j) acc[i][j] = (f32x4){0.f, 0.f, 0.f, 0.f};

  const int T = K / BK;  // 32
  STAGE(0, 0);
  STAGE(1, 1);
  STAGE(2, 2);

  for (int t = 0; t < T; ++t) {
    // tile t resident when at most (tiles issued after t)*4 loads outstanding
    if (t <= T - 3) { VMCNT(8); } else if (t == T - 2) { VMCNT(4); } else { VMCNT(0); }
    __builtin_amdgcn_s_barrier();
    FENCE();
    if (t + 3 < T) STAGE((t + 3) & 3, t + 3);  // writes buf[(t-1)&3]: reads done pre-barrier

    const char* ab = smem + (size_t)(t & 3) * TILE_BYTES;
    bf16x8 a[8], b[4];
#pragma unroll
    for (int j = 0; j < 4; ++j) b[j] = *(const bf16x8*)(ab + bBase + j * 1024);
#pragma unroll
    for (int i = 0; i < 4; ++i) a[i] = *(const bf16x8*)(ab + aBase + i * 1024);

    __builtin_amdgcn_s_setprio(1);
#pragma unroll
    for (int i = 0; i < 4; ++i)
#pragma unroll
      for (int j = 0; j < 4; ++j)
        acc[i][j] = __builtin_amdgcn_mfma_f32_16x16x32_bf16(a[i], b[j], acc[i][j], 0, 0, 0);
    __builtin_amdgcn_s_setprio(0);

#pragma unroll
    for (int i = 4; i < 8; ++i) a[i] = *(const bf16x8*)(ab + aBase + i * 1024);

    __builtin_amdgcn_s_setprio(1);
#pragma unroll
    for (int i = 4; i < 8; ++i)
#pragma unroll
      for (int j = 0; j < 4; ++j)
        acc[i][j] = __builtin_amdgcn_mfma_f32_16x16x32_bf16(a[i], b[j], acc[i][j], 0, 0, 0);
    __builtin_amdgcn_s_setprio(0);
  }
#undef STAGE

  // epilogue: C[row][col] = acc + bias[col]
#pragma unroll
  for (int j = 0; j < 4; ++j) {
    const int col = n0 + wn * 64 + j * 16 + fr;
    const float bv = bias[col];
#pragma unroll
    for (int i = 0; i < 8; ++i) {
      const int row0 = m0 + wm * 128 + i * 16 + hi * 4;
#pragma unroll
      for (int r = 0; r < 4; ++r)
        C[(size_t)(row0 + r) * N + col] = acc[i][j][r] + bv;
    }
  }
}

extern "C" void kernel_launch(void* const* d_in, const int* in_sizes, int n_in,
                              void* d_out, int out_size, void* d_ws, size_t ws_size,
                              hipStream_t stream) {
  const float* x = (const float*)d_in[0];     // [M,K]
  const float* w = (const float*)d_in[1];     // [N,K]
  const float* bias = (const float*)d_in[2];  // [N]
  float* out = (float*)d_out;

  const int MK = in_sizes[0];
  const int NK = in_sizes[1];
  const int N = in_sizes[2];
  const int K = NK / N;
  const int M = MK / K;

  __hip_bfloat16* qx = (__hip_bfloat16*)d_ws;
  __hip_bfloat16* qw = qx + (size_t)MK;

  const int gx = MK / 256;
  const int gw = NK / 256;
  qdq_kernel<<<(gx + 3) / 4, 256, 0, stream>>>(x, qx, gx);
  qdq_kernel<<<(gw + 3) / 4, 256, 0, stream>>>(w, qw, gw);

  hipFuncSetAttribute((const void*)gemm256, hipFuncAttributeMaxDynamicSharedMemorySize,
                      NBUF * TILE_BYTES);
  dim3 grid((M / BM) * (N / BN));
  gemm256<<<grid, dim3(THREADS), NBUF * TILE_BYTES, stream>>>(qx, qw, bias, out, M, N, K);
}